// Round 5
// baseline (444.374 us; speedup 1.0000x reference)
//
#include <hip/hip_runtime.h>
#include <hip/hip_bf16.h>

#define NN 100000
#define NE 1600000
#define D 128
#define KTOT 640
#define LN_EPS 1e-5f

#define SCAN_CHUNK 2048
#define NSB 49           // ceil(NN / SCAN_CHUNK)

#define NBK 98           // dst buckets (dst >> 10), 1024 nodes each
#define BCAP 20480       // slots per bucket (avg fill 16.3K, sigma ~126)

// ---- workspace layout (bytes) ----
#define WS_OFF_OFF   0          // 100352 int (pad absorbs tail writes)
#define WS_OFF_CUR   401408     // 100352 int (memset 0; post-scatter = per-node count)
#define WS_OFF_BSUM  802816     // 64 int
#define WS_OFF_GCUR  803072     // 128 int (memset 0)
#define WS_OFF_WCBF  803584     // 128*640 u16 = 163840
#define WS_OFF_ESRC  967680     // 1.7M int
#define WS_OFF_GBUF  7768064    // 98*20480*8 = 16056320, then reused as hhi
#define WS_OFF_HHI   7768064    // NN*128 u16 = 25600000
#define WS_OFF_NB1   33368064   // NN*128 u16 = 25600000 (end 58968064)

typedef __attribute__((ext_vector_type(8))) short bf16x8;
typedef __attribute__((ext_vector_type(4))) float f32x4;

__device__ __forceinline__ unsigned short f2bf(float f) {
    unsigned u = __float_as_uint(f);
    unsigned r = (u + 0x7FFFu + ((u >> 16) & 1u)) >> 16;
    return (unsigned short)r;
}
__device__ __forceinline__ float bf2f(unsigned short b) {
    return __uint_as_float(((unsigned)b) << 16);
}

// split 8 fp32 -> hi bf16x8 + lo bf16x8 (two-term expansion)
__device__ __forceinline__ void split8(float4 va, float4 vb, bf16x8& hi, bf16x8& lo) {
    float v[8] = {va.x, va.y, va.z, va.w, vb.x, vb.y, vb.z, vb.w};
    #pragma unroll
    for (int j = 0; j < 8; ++j) {
        unsigned short hb = f2bf(v[j]);
        hi[j] = (short)hb;
        lo[j] = (short)f2bf(v[j] - bf2f(hb));
    }
}

__global__ void k_prep(const float* __restrict__ h, unsigned int* __restrict__ hhi) {
    int i = blockIdx.x * blockDim.x + threadIdx.x;   // 6.4M dwords
    float2 v = reinterpret_cast<const float2*>(h)[i];
    hhi[i] = (unsigned)f2bf(v.x) | ((unsigned)f2bf(v.y) << 16);
}

// pass 1: scan int(deg) per 2048-chunk -> off (local excl), block total -> bsum
__global__ __launch_bounds__(256) void k_scan1(const float* __restrict__ deg,
                                               int* __restrict__ off,
                                               int* __restrict__ bsum) {
    __shared__ int lds[256];
    int t = threadIdx.x, b = blockIdx.x;
    int base = b * SCAN_CHUNK + t * 8;
    int v[8];
    if (base < NN) {   // NN % 8 == 0
        float4 a0 = reinterpret_cast<const float4*>(deg + base)[0];
        float4 a1 = reinterpret_cast<const float4*>(deg + base)[1];
        v[0] = __float2int_rn(a0.x); v[1] = __float2int_rn(a0.y);
        v[2] = __float2int_rn(a0.z); v[3] = __float2int_rn(a0.w);
        v[4] = __float2int_rn(a1.x); v[5] = __float2int_rn(a1.y);
        v[6] = __float2int_rn(a1.z); v[7] = __float2int_rn(a1.w);
    } else {
        #pragma unroll
        for (int j = 0; j < 8; ++j) v[j] = 0;
    }
    int s = 0;
    #pragma unroll
    for (int j = 0; j < 8; ++j) s += v[j];
    lds[t] = s;
    __syncthreads();
    for (int ofs = 1; ofs < 256; ofs <<= 1) {
        int x = (t >= ofs) ? lds[t - ofs] : 0;
        __syncthreads();
        lds[t] += x;
        __syncthreads();
    }
    int excl = (t == 0) ? 0 : lds[t - 1];
    #pragma unroll
    for (int j = 0; j < 8; ++j) { off[base + j] = excl; excl += v[j]; }
    if (t == 255) bsum[b] = lds[255];
}

__global__ void k_scan2(int* __restrict__ bsum) {
    int t = threadIdx.x;
    int v = (t < NSB) ? bsum[t] : 0;
    #pragma unroll
    for (int ofs = 1; ofs < 64; ofs <<= 1) {
        int x = __shfl_up(v, ofs, 64);
        if (t >= ofs) v += x;
    }
    int excl = __shfl_up(v, 1, 64);
    if (t == 0) excl = 0;
    if (t < NSB) bsum[t] = excl;
    if (t == NSB - 1) bsum[NSB] = v;
}

__global__ void k_scan3(int* __restrict__ off, const int* __restrict__ bsum) {
    int i = blockIdx.x * blockDim.x + threadIdx.x;
    if (i < NN) off[i] += bsum[i >> 11];
    if (i == 0) off[NN] = bsum[NSB];
}

// binning pass A: edges -> 98 dst-range buckets, LDS-aggregated ranks
__global__ __launch_bounds__(256) void k_bin(const int* __restrict__ src,
                                             const int* __restrict__ dst,
                                             int* __restrict__ gcur,
                                             int2* __restrict__ gbuf) {
    __shared__ int bcnt[NBK];
    __shared__ int bbase[NBK];
    int t = threadIdx.x;
    if (t < NBK) bcnt[t] = 0;
    __syncthreads();
    int e0 = blockIdx.x * 2048;
    int s[8], d[8], r[8];
    #pragma unroll
    for (int it = 0; it < 8; ++it) {
        int e = e0 + it * 256 + t;
        bool ok = e < NE;
        s[it] = ok ? src[e] : 0;
        d[it] = ok ? dst[e] : -1;
        r[it] = ok ? atomicAdd(&bcnt[d[it] >> 10], 1) : 0;
    }
    __syncthreads();
    if (t < NBK) bbase[t] = atomicAdd(&gcur[t], bcnt[t]);
    __syncthreads();
    #pragma unroll
    for (int it = 0; it < 8; ++it) {
        if (d[it] >= 0) {
            int bk = d[it] >> 10;
            gbuf[(size_t)bk * BCAP + bbase[bk] + r[it]] = make_int2(s[it], d[it]);
        }
    }
}

// scatter pass B: one block per bucket; esrc/cur writes stay in a ~70KB L2 window
__global__ __launch_bounds__(1024) void k_scatter2(const int2* __restrict__ gbuf,
                                                   const int* __restrict__ gcur,
                                                   const int* __restrict__ off,
                                                   int* __restrict__ cur,
                                                   int* __restrict__ esrc) {
    int b = blockIdx.x;
    int nb = gcur[b];
    const int2* bb = gbuf + (size_t)b * BCAP;
    for (int i = threadIdx.x; i < nb; i += 1024) {
        int2 e = bb[i];
        int p = off[e.y] + atomicAdd(&cur[e.y], 1);
        esrc[p] = e.x;
    }
}

// combined weights -> bf16, [o][640]: segs {Wc1, Wc1, Wc2, Wc3, Wc3}
__global__ void k_weights(const float* __restrict__ Ws, const float* __restrict__ W1,
                          const float* __restrict__ Whp, const float* __restrict__ W2,
                          const float* __restrict__ logits, unsigned short* __restrict__ wcbf) {
    int idx = blockIdx.x * blockDim.x + threadIdx.x;
    if (idx >= D * D) return;
    int o = idx >> 7, k = idx & 127;
    float s0 = 2.f / (1.f + __expf(-logits[0]));
    float s1 = 2.f / (1.f + __expf(-logits[1]));
    float s2 = 2.f / (1.f + __expf(-logits[2]));
    float s3 = 2.f / (1.f + __expf(-logits[3]));
    unsigned short b1 = f2bf(s0 * Ws[idx] + s2 * Whp[idx]);
    unsigned short b2 = f2bf(s1 * W1[idx] - s2 * Whp[idx]);
    unsigned short b3 = f2bf(s3 * W2[idx]);
    size_t base = (size_t)o * KTOT + k;
    wcbf[base]       = b1;   // h_hi
    wcbf[base + 128] = b1;   // h_lo
    wcbf[base + 256] = b2;   // nb1
    wcbf[base + 384] = b3;   // nb2_hi
    wcbf[base + 512] = b3;   // nb2_lo
}

// one wave per node; lane owns 2 dims packed in one dword (bf16 pair).
template <bool OUT_F32>
__global__ __launch_bounds__(256) void k_hop(const unsigned int* __restrict__ in,
                                             void* __restrict__ outv,
                                             const int* __restrict__ off,
                                             const int* __restrict__ cnt_arr,
                                             const int* __restrict__ esrc,
                                             const float* __restrict__ deg) {
    int w = (blockIdx.x * blockDim.x + threadIdx.x) >> 6;
    int lane = threadIdx.x & 63;
    int beg = __builtin_amdgcn_readfirstlane(off[w]);
    int cnt = __builtin_amdgcn_readfirstlane(cnt_arr[w]);
    float ax = 0.f, ay = 0.f;
    for (int base = 0; base < cnt; base += 64) {
        int m = cnt - base; if (m > 64) m = 64;
        int ev = esrc[beg + base + (lane < m ? lane : 0)];
        int j = 0;
        for (; j + 8 <= m; j += 8) {
            int s0 = __builtin_amdgcn_readlane(ev, j + 0);
            int s1 = __builtin_amdgcn_readlane(ev, j + 1);
            int s2 = __builtin_amdgcn_readlane(ev, j + 2);
            int s3 = __builtin_amdgcn_readlane(ev, j + 3);
            int s4 = __builtin_amdgcn_readlane(ev, j + 4);
            int s5 = __builtin_amdgcn_readlane(ev, j + 5);
            int s6 = __builtin_amdgcn_readlane(ev, j + 6);
            int s7 = __builtin_amdgcn_readlane(ev, j + 7);
            unsigned u0 = in[(size_t)s0 * 64 + lane];
            unsigned u1 = in[(size_t)s1 * 64 + lane];
            unsigned u2 = in[(size_t)s2 * 64 + lane];
            unsigned u3 = in[(size_t)s3 * 64 + lane];
            unsigned u4 = in[(size_t)s4 * 64 + lane];
            unsigned u5 = in[(size_t)s5 * 64 + lane];
            unsigned u6 = in[(size_t)s6 * 64 + lane];
            unsigned u7 = in[(size_t)s7 * 64 + lane];
            ax += __uint_as_float(u0 << 16);  ay += __uint_as_float(u0 & 0xffff0000u);
            ax += __uint_as_float(u1 << 16);  ay += __uint_as_float(u1 & 0xffff0000u);
            ax += __uint_as_float(u2 << 16);  ay += __uint_as_float(u2 & 0xffff0000u);
            ax += __uint_as_float(u3 << 16);  ay += __uint_as_float(u3 & 0xffff0000u);
            ax += __uint_as_float(u4 << 16);  ay += __uint_as_float(u4 & 0xffff0000u);
            ax += __uint_as_float(u5 << 16);  ay += __uint_as_float(u5 & 0xffff0000u);
            ax += __uint_as_float(u6 << 16);  ay += __uint_as_float(u6 & 0xffff0000u);
            ax += __uint_as_float(u7 << 16);  ay += __uint_as_float(u7 & 0xffff0000u);
        }
        for (; j < m; ++j) {
            int s0 = __builtin_amdgcn_readlane(ev, j);
            unsigned u0 = in[(size_t)s0 * 64 + lane];
            ax += __uint_as_float(u0 << 16);  ay += __uint_as_float(u0 & 0xffff0000u);
        }
    }
    float inv = 1.0f / deg[w];
    ax *= inv; ay *= inv;
    if (OUT_F32) {
        float2 p; p.x = ax; p.y = ay;
        reinterpret_cast<float2*>(outv)[(size_t)w * 64 + lane] = p;
    } else {
        reinterpret_cast<unsigned int*>(outv)[(size_t)w * 64 + lane] =
            (unsigned)f2bf(ax) | ((unsigned)f2bf(ay) << 16);
    }
}

// MFMA GEMM (M=64/block, N=128, K=640) + fused LayerNorm. No operand LDS:
// A-frags loaded direct global->reg (16 rows x 64B contiguous per instr), hi/lo
// split of fp32 h / nb2 done in registers. B cached in regs per 320-K chunk.
// LN via lm-group butterflies + 2.6KB LDS partials; stores straight from acc.
__global__ __launch_bounds__(256, 2) void k_gemm_ln(
    const float* __restrict__ hf, const unsigned int* __restrict__ nb1u,
    const float* __restrict__ nb2f, const unsigned short* __restrict__ wcbf,
    const float* __restrict__ bias, const float* __restrict__ gamma,
    const float* __restrict__ beta, float* __restrict__ out) {
    __shared__ float part_s[4][64];
    __shared__ float part_q[4][64];
    __shared__ float mu_s[64], rs_s[64];

    const int t = threadIdx.x;
    const int wv = t >> 6, lane = t & 63;
    const int lm = lane & 15, quad = lane >> 4;
    const int node0 = blockIdx.x * 64;
    const unsigned short* nb1s = reinterpret_cast<const unsigned short*>(nb1u);

    size_t rof[4];
    int rrow[4];
    #pragma unroll
    for (int mt = 0; mt < 4; ++mt) {
        int r = node0 + mt * 16 + lm;
        rrow[mt] = r;
        rof[mt] = (size_t)(r < NN ? r : NN - 1) * D;
    }

    f32x4 acc[4][2] = {};

    const int obase = wv * 32;
    #pragma unroll
    for (int c = 0; c < 2; ++c) {
        bf16x8 bfr[2][10];
        #pragma unroll
        for (int nt = 0; nt < 2; ++nt) {
            const unsigned short* wp = wcbf + (size_t)(obase + nt * 16 + lm) * KTOT + c * 320 + quad * 8;
            #pragma unroll
            for (int s = 0; s < 10; ++s)
                bfr[nt][s] = *reinterpret_cast<const bf16x8*>(wp + s * 32);
        }
        #pragma unroll
        for (int mt = 0; mt < 4; ++mt) {
            bf16x8 afr[10];
            if (c == 0) {
                float4 fa[4], fb[4];
                #pragma unroll
                for (int s = 0; s < 4; ++s) {
                    const float* p = hf + rof[mt] + s * 32 + quad * 8;
                    fa[s] = *reinterpret_cast<const float4*>(p);
                    fb[s] = *reinterpret_cast<const float4*>(p + 4);
                }
                const unsigned short* np = nb1s + rof[mt] + quad * 8;
                bf16x8 n0 = *reinterpret_cast<const bf16x8*>(np);
                bf16x8 n1 = *reinterpret_cast<const bf16x8*>(np + 32);
                #pragma unroll
                for (int s = 0; s < 4; ++s) split8(fa[s], fb[s], afr[s], afr[4 + s]);
                afr[8] = n0; afr[9] = n1;
            } else {
                const unsigned short* np = nb1s + rof[mt] + 64 + quad * 8;
                bf16x8 n0 = *reinterpret_cast<const bf16x8*>(np);
                bf16x8 n1 = *reinterpret_cast<const bf16x8*>(np + 32);
                float4 fa[4], fb[4];
                #pragma unroll
                for (int s = 0; s < 4; ++s) {
                    const float* p = nb2f + rof[mt] + s * 32 + quad * 8;
                    fa[s] = *reinterpret_cast<const float4*>(p);
                    fb[s] = *reinterpret_cast<const float4*>(p + 4);
                }
                afr[0] = n0; afr[1] = n1;
                #pragma unroll
                for (int s = 0; s < 4; ++s) split8(fa[s], fb[s], afr[2 + s], afr[6 + s]);
            }
            #pragma unroll
            for (int s = 0; s < 10; ++s) {
                acc[mt][0] = __builtin_amdgcn_mfma_f32_16x16x32_bf16(afr[s], bfr[0][s], acc[mt][0], 0, 0, 0);
                acc[mt][1] = __builtin_amdgcn_mfma_f32_16x16x32_bf16(afr[s], bfr[1][s], acc[mt][1], 0, 0, 0);
            }
        }
    }

    // ---- LN: add bias, butterfly partial row-sums over this wave's 32 cols ----
    float bv0 = bias[obase + lm], bv1 = bias[obase + 16 + lm];
    #pragma unroll
    for (int mt = 0; mt < 4; ++mt) {
        float s[4], q[4];
        #pragma unroll
        for (int r = 0; r < 4; ++r) {
            float v0 = acc[mt][0][r] + bv0;
            float v1 = acc[mt][1][r] + bv1;
            acc[mt][0][r] = v0;  acc[mt][1][r] = v1;
            s[r] = v0 + v1;
            q[r] = v0 * v0 + v1 * v1;
        }
        #pragma unroll
        for (int off = 1; off < 16; off <<= 1) {
            #pragma unroll
            for (int r = 0; r < 4; ++r) {
                s[r] += __shfl_xor(s[r], off, 64);
                q[r] += __shfl_xor(q[r], off, 64);
            }
        }
        if (lm == 0) {
            #pragma unroll
            for (int r = 0; r < 4; ++r) {
                part_s[wv][mt * 16 + quad * 4 + r] = s[r];
                part_q[wv][mt * 16 + quad * 4 + r] = q[r];
            }
        }
    }
    __syncthreads();
    if (t < 64) {
        float s = part_s[0][t] + part_s[1][t] + part_s[2][t] + part_s[3][t];
        float q = part_q[0][t] + part_q[1][t] + part_q[2][t] + part_q[3][t];
        float m = s * (1.f / 128.f);
        float var = q * (1.f / 128.f) - m * m;
        mu_s[t] = m;
        rs_s[t] = rsqrtf(var + LN_EPS);
    }
    __syncthreads();

    float g0 = gamma[obase + lm], g1 = gamma[obase + 16 + lm];
    float e0 = beta[obase + lm],  e1 = beta[obase + 16 + lm];
    #pragma unroll
    for (int mt = 0; mt < 4; ++mt) {
        #pragma unroll
        for (int r = 0; r < 4; ++r) {
            int lrow = mt * 16 + quad * 4 + r;
            int grow = node0 + lrow;
            if (grow < NN) {
                float mu = mu_s[lrow], rs = rs_s[lrow];
                out[(size_t)grow * D + obase + lm]      = (acc[mt][0][r] - mu) * rs * g0 + e0;
                out[(size_t)grow * D + obase + 16 + lm] = (acc[mt][1][r] - mu) * rs * g1 + e1;
            }
        }
    }
}

extern "C" void kernel_launch(void* const* d_in, const int* in_sizes, int n_in,
                              void* d_out, int out_size, void* d_ws, size_t ws_size,
                              hipStream_t stream) {
    const float* h      = (const float*)d_in[0];
    const int*   ei     = (const int*)d_in[1];
    const float* deg    = (const float*)d_in[2];
    const float* Wself  = (const float*)d_in[3];
    const float* Wnb1   = (const float*)d_in[4];
    const float* Whp    = (const float*)d_in[5];
    const float* Wnb2   = (const float*)d_in[6];
    const float* bias   = (const float*)d_in[7];
    const float* logits = (const float*)d_in[8];
    const float* gamma  = (const float*)d_in[9];
    const float* beta   = (const float*)d_in[10];
    float* out = (float*)d_out;

    char* ws = (char*)d_ws;
    int* off                 = (int*)(ws + WS_OFF_OFF);
    int* cur                 = (int*)(ws + WS_OFF_CUR);
    int* bsum                = (int*)(ws + WS_OFF_BSUM);
    int* gcur                = (int*)(ws + WS_OFF_GCUR);
    unsigned short* wcbf     = (unsigned short*)(ws + WS_OFF_WCBF);
    int* esrc                = (int*)(ws + WS_OFF_ESRC);
    int2* gbuf               = (int2*)(ws + WS_OFF_GBUF);
    unsigned int* hhi        = (unsigned int*)(ws + WS_OFF_HHI);
    unsigned int* nb1u       = (unsigned int*)(ws + WS_OFF_NB1);

    const int* src = ei;
    const int* dst = ei + NE;

    hipMemsetAsync(cur, 0, NN * sizeof(int), stream);
    hipMemsetAsync(gcur, 0, NBK * sizeof(int), stream);

    k_weights<<<64, 256, 0, stream>>>(Wself, Wnb1, Whp, Wnb2, logits, wcbf);
    k_scan1<<<NSB, 256, 0, stream>>>(deg, off, bsum);
    k_scan2<<<1, 64, 0, stream>>>(bsum);
    k_scan3<<<(NN + 255) / 256, 256, 0, stream>>>(off, bsum);
    k_bin<<<(NE + 2047) / 2048, 256, 0, stream>>>(src, dst, gcur, gbuf);
    k_scatter2<<<NBK, 1024, 0, stream>>>(gbuf, gcur, off, cur, esrc);

    // prep AFTER scatter2: hhi overlays the (now dead) gbuf region
    k_prep<<<25000, 256, 0, stream>>>(h, hhi);

    // hop1: gather h_hi (bf16) -> nb1_hi (bf16, ws)
    k_hop<false><<<(NN * 64) / 256, 256, 0, stream>>>(hhi, (void*)nb1u, off, cur, esrc, deg);
    // hop2: gather nb1_hi (bf16) -> nb2 (fp32, d_out scratch; gemm block reads
    // only its own rows then overwrites them — self-contained)
    k_hop<true><<<(NN * 64) / 256, 256, 0, stream>>>(nb1u, (void*)out, off, cur, esrc, deg);

    k_gemm_ln<<<(NN + 63) / 64, 256, 0, stream>>>(h, nb1u, out, wcbf, bias, gamma, beta, out);
}

// Round 6
// 414.176 us; speedup vs baseline: 1.0729x; 1.0729x over previous
//
#include <hip/hip_runtime.h>
#include <hip/hip_bf16.h>

#define NN 100000
#define NE 1600000
#define D 128
#define KTOT 640
#define LN_EPS 1e-5f

#define PITCH_US 328     // ushorts per staged row (320 + 8 pad); 164 dw, 164%32=4
#define PITCH_DW 164

#define SCAN_CHUNK 2048
#define NSB 49           // ceil(NN / SCAN_CHUNK)

#define NBK 98           // dst buckets (dst >> 10), 1024 nodes each
#define BCAP 20480       // slots per bucket (avg fill 16.3K, sigma ~126)

// ---- workspace layout (bytes) ----
#define WS_OFF_OFF   0          // 100352 int (pad absorbs tail writes)
#define WS_OFF_CUR   401408     // 100352 int (memset 0; post-scatter = per-node count)
#define WS_OFF_BSUM  802816     // 64 int
#define WS_OFF_GCUR  803072     // 128 int (memset 0)
#define WS_OFF_WCBF  803584     // 128*640 u16 = 163840
#define WS_OFF_ESRC  967680     // 1.7M int
#define WS_OFF_GBUF  7768064    // 98*20480*8 = 16056320, then reused as hhi
#define WS_OFF_HHI   7768064    // NN*128 u16 = 25600000
#define WS_OFF_NB1   33368064   // NN*128 u16 = 25600000 (end 58968064)

typedef __attribute__((ext_vector_type(8))) short bf16x8;
typedef __attribute__((ext_vector_type(4))) float f32x4;

__device__ __forceinline__ unsigned short f2bf(float f) {
    unsigned u = __float_as_uint(f);
    unsigned r = (u + 0x7FFFu + ((u >> 16) & 1u)) >> 16;
    return (unsigned short)r;
}
__device__ __forceinline__ float bf2f(unsigned short b) {
    return __uint_as_float(((unsigned)b) << 16);
}

__global__ void k_prep(const float* __restrict__ h, unsigned int* __restrict__ hhi) {
    int i = blockIdx.x * blockDim.x + threadIdx.x;   // 6.4M dwords
    float2 v = reinterpret_cast<const float2*>(h)[i];
    hhi[i] = (unsigned)f2bf(v.x) | ((unsigned)f2bf(v.y) << 16);
}

// pass 1: scan int(deg) per 2048-chunk -> off (local excl), block total -> bsum
__global__ __launch_bounds__(256) void k_scan1(const float* __restrict__ deg,
                                               int* __restrict__ off,
                                               int* __restrict__ bsum) {
    __shared__ int lds[256];
    int t = threadIdx.x, b = blockIdx.x;
    int base = b * SCAN_CHUNK + t * 8;
    int v[8];
    if (base < NN) {   // NN % 8 == 0
        float4 a0 = reinterpret_cast<const float4*>(deg + base)[0];
        float4 a1 = reinterpret_cast<const float4*>(deg + base)[1];
        v[0] = __float2int_rn(a0.x); v[1] = __float2int_rn(a0.y);
        v[2] = __float2int_rn(a0.z); v[3] = __float2int_rn(a0.w);
        v[4] = __float2int_rn(a1.x); v[5] = __float2int_rn(a1.y);
        v[6] = __float2int_rn(a1.z); v[7] = __float2int_rn(a1.w);
    } else {
        #pragma unroll
        for (int j = 0; j < 8; ++j) v[j] = 0;
    }
    int s = 0;
    #pragma unroll
    for (int j = 0; j < 8; ++j) s += v[j];
    lds[t] = s;
    __syncthreads();
    for (int ofs = 1; ofs < 256; ofs <<= 1) {
        int x = (t >= ofs) ? lds[t - ofs] : 0;
        __syncthreads();
        lds[t] += x;
        __syncthreads();
    }
    int excl = (t == 0) ? 0 : lds[t - 1];
    #pragma unroll
    for (int j = 0; j < 8; ++j) { off[base + j] = excl; excl += v[j]; }
    if (t == 255) bsum[b] = lds[255];
}

__global__ void k_scan2(int* __restrict__ bsum) {
    int t = threadIdx.x;
    int v = (t < NSB) ? bsum[t] : 0;
    #pragma unroll
    for (int ofs = 1; ofs < 64; ofs <<= 1) {
        int x = __shfl_up(v, ofs, 64);
        if (t >= ofs) v += x;
    }
    int excl = __shfl_up(v, 1, 64);
    if (t == 0) excl = 0;
    if (t < NSB) bsum[t] = excl;
    if (t == NSB - 1) bsum[NSB] = v;
}

__global__ void k_scan3(int* __restrict__ off, const int* __restrict__ bsum) {
    int i = blockIdx.x * blockDim.x + threadIdx.x;
    if (i < NN) off[i] += bsum[i >> 11];
    if (i == 0) off[NN] = bsum[NSB];
}

// binning pass A: edges -> 98 dst-range buckets, LDS-aggregated ranks
__global__ __launch_bounds__(256) void k_bin(const int* __restrict__ src,
                                             const int* __restrict__ dst,
                                             int* __restrict__ gcur,
                                             int2* __restrict__ gbuf) {
    __shared__ int bcnt[NBK];
    __shared__ int bbase[NBK];
    int t = threadIdx.x;
    if (t < NBK) bcnt[t] = 0;
    __syncthreads();
    int e0 = blockIdx.x * 2048;
    int s[8], d[8], r[8];
    #pragma unroll
    for (int it = 0; it < 8; ++it) {
        int e = e0 + it * 256 + t;
        bool ok = e < NE;
        s[it] = ok ? src[e] : 0;
        d[it] = ok ? dst[e] : -1;
        r[it] = ok ? atomicAdd(&bcnt[d[it] >> 10], 1) : 0;
    }
    __syncthreads();
    if (t < NBK) bbase[t] = atomicAdd(&gcur[t], bcnt[t]);
    __syncthreads();
    #pragma unroll
    for (int it = 0; it < 8; ++it) {
        if (d[it] >= 0) {
            int bk = d[it] >> 10;
            gbuf[(size_t)bk * BCAP + bbase[bk] + r[it]] = make_int2(s[it], d[it]);
        }
    }
}

// scatter pass B: one block per bucket; esrc/cur writes stay in a ~70KB L2 window
__global__ __launch_bounds__(1024) void k_scatter2(const int2* __restrict__ gbuf,
                                                   const int* __restrict__ gcur,
                                                   const int* __restrict__ off,
                                                   int* __restrict__ cur,
                                                   int* __restrict__ esrc) {
    int b = blockIdx.x;
    int nb = gcur[b];
    const int2* bb = gbuf + (size_t)b * BCAP;
    for (int i = threadIdx.x; i < nb; i += 1024) {
        int2 e = bb[i];
        int p = off[e.y] + atomicAdd(&cur[e.y], 1);
        esrc[p] = e.x;
    }
}

// combined weights -> bf16, [o][640]: segs {Wc1, Wc1, Wc2, Wc3, Wc3}
__global__ void k_weights(const float* __restrict__ Ws, const float* __restrict__ W1,
                          const float* __restrict__ Whp, const float* __restrict__ W2,
                          const float* __restrict__ logits, unsigned short* __restrict__ wcbf) {
    int idx = blockIdx.x * blockDim.x + threadIdx.x;
    if (idx >= D * D) return;
    int o = idx >> 7, k = idx & 127;
    float s0 = 2.f / (1.f + __expf(-logits[0]));
    float s1 = 2.f / (1.f + __expf(-logits[1]));
    float s2 = 2.f / (1.f + __expf(-logits[2]));
    float s3 = 2.f / (1.f + __expf(-logits[3]));
    unsigned short b1 = f2bf(s0 * Ws[idx] + s2 * Whp[idx]);
    unsigned short b2 = f2bf(s1 * W1[idx] - s2 * Whp[idx]);
    unsigned short b3 = f2bf(s3 * W2[idx]);
    size_t base = (size_t)o * KTOT + k;
    wcbf[base]       = b1;   // h_hi
    wcbf[base + 128] = b1;   // h_lo
    wcbf[base + 256] = b2;   // nb1
    wcbf[base + 384] = b3;   // nb2_hi
    wcbf[base + 512] = b3;   // nb2_lo
}

// one wave per node; lane owns 2 dims packed in one dword (bf16 pair).
template <bool OUT_F32>
__global__ __launch_bounds__(256) void k_hop(const unsigned int* __restrict__ in,
                                             void* __restrict__ outv,
                                             const int* __restrict__ off,
                                             const int* __restrict__ cnt_arr,
                                             const int* __restrict__ esrc,
                                             const float* __restrict__ deg) {
    int w = (blockIdx.x * blockDim.x + threadIdx.x) >> 6;
    int lane = threadIdx.x & 63;
    int beg = __builtin_amdgcn_readfirstlane(off[w]);
    int cnt = __builtin_amdgcn_readfirstlane(cnt_arr[w]);
    float ax = 0.f, ay = 0.f;
    for (int base = 0; base < cnt; base += 64) {
        int m = cnt - base; if (m > 64) m = 64;
        int ev = esrc[beg + base + (lane < m ? lane : 0)];
        int j = 0;
        for (; j + 8 <= m; j += 8) {
            int s0 = __builtin_amdgcn_readlane(ev, j + 0);
            int s1 = __builtin_amdgcn_readlane(ev, j + 1);
            int s2 = __builtin_amdgcn_readlane(ev, j + 2);
            int s3 = __builtin_amdgcn_readlane(ev, j + 3);
            int s4 = __builtin_amdgcn_readlane(ev, j + 4);
            int s5 = __builtin_amdgcn_readlane(ev, j + 5);
            int s6 = __builtin_amdgcn_readlane(ev, j + 6);
            int s7 = __builtin_amdgcn_readlane(ev, j + 7);
            unsigned u0 = in[(size_t)s0 * 64 + lane];
            unsigned u1 = in[(size_t)s1 * 64 + lane];
            unsigned u2 = in[(size_t)s2 * 64 + lane];
            unsigned u3 = in[(size_t)s3 * 64 + lane];
            unsigned u4 = in[(size_t)s4 * 64 + lane];
            unsigned u5 = in[(size_t)s5 * 64 + lane];
            unsigned u6 = in[(size_t)s6 * 64 + lane];
            unsigned u7 = in[(size_t)s7 * 64 + lane];
            ax += __uint_as_float(u0 << 16);  ay += __uint_as_float(u0 & 0xffff0000u);
            ax += __uint_as_float(u1 << 16);  ay += __uint_as_float(u1 & 0xffff0000u);
            ax += __uint_as_float(u2 << 16);  ay += __uint_as_float(u2 & 0xffff0000u);
            ax += __uint_as_float(u3 << 16);  ay += __uint_as_float(u3 & 0xffff0000u);
            ax += __uint_as_float(u4 << 16);  ay += __uint_as_float(u4 & 0xffff0000u);
            ax += __uint_as_float(u5 << 16);  ay += __uint_as_float(u5 & 0xffff0000u);
            ax += __uint_as_float(u6 << 16);  ay += __uint_as_float(u6 & 0xffff0000u);
            ax += __uint_as_float(u7 << 16);  ay += __uint_as_float(u7 & 0xffff0000u);
        }
        for (; j < m; ++j) {
            int s0 = __builtin_amdgcn_readlane(ev, j);
            unsigned u0 = in[(size_t)s0 * 64 + lane];
            ax += __uint_as_float(u0 << 16);  ay += __uint_as_float(u0 & 0xffff0000u);
        }
    }
    float inv = 1.0f / deg[w];
    ax *= inv; ay *= inv;
    if (OUT_F32) {
        float2 p; p.x = ax; p.y = ay;
        reinterpret_cast<float2*>(outv)[(size_t)w * 64 + lane] = p;
    } else {
        reinterpret_cast<unsigned int*>(outv)[(size_t)w * 64 + lane] =
            (unsigned)f2bf(ax) | ((unsigned)f2bf(ay) << 16);
    }
}

// MFMA GEMM (M=32/block, N=128, K=640 in two 320-K LDS chunks) + fused LN.
// Chunk 0 = [h_hi | h_lo | nb1[0:64]], chunk 1 = [nb1[64:128] | nb2_hi | nb2_lo]
// (matches wcbf column order). 21KB LDS buffer -> 7 blocks/CU resident.
// LN epilogue in registers (lm-butterfly + 1KB LDS partials), no zs roundtrip.
__global__ __launch_bounds__(256) void k_gemm_ln(
    const unsigned int* __restrict__ hhi, const float* __restrict__ hf,
    const unsigned int* __restrict__ nb1u, const float* __restrict__ nb2f,
    const unsigned short* __restrict__ wcbf, const float* __restrict__ bias,
    const float* __restrict__ gamma, const float* __restrict__ beta,
    float* __restrict__ out) {
    __shared__ __align__(16) unsigned short Xs[32 * PITCH_US];   // 20992 B
    __shared__ float part_s[4][32];
    __shared__ float part_q[4][32];
    __shared__ float mu_s[32], rs_s[32];
    unsigned int* Xs_u = reinterpret_cast<unsigned int*>(Xs);

    const int t = threadIdx.x;
    const int wv = t >> 6, lane = t & 63;
    const int lm = lane & 15, quad = lane >> 4;
    const int node0 = blockIdx.x * 32;
    const int obase = wv * 32;

    f32x4 acc[2][2] = {};

    #pragma unroll
    for (int c = 0; c < 2; ++c) {
        if (c == 0) {
            // ---- stage chunk 0: h_hi (dw 0..63), h_lo (64..127), nb1[0:32dw] (128..159)
            #pragma unroll
            for (int it = 0; it < 8; ++it) {
                int i = t + 256 * it;
                int row = i >> 6, d = i & 63;
                size_t g = (size_t)(node0 + row) * 64 + d;
                int lb = row * PITCH_DW + d;
                unsigned hh = hhi[g];
                Xs_u[lb] = hh;
                float2 hv = reinterpret_cast<const float2*>(hf)[g];
                Xs_u[lb + 64] =
                      (unsigned)f2bf(hv.x - bf2f((unsigned short)(hh & 0xffffu)))
                    | ((unsigned)f2bf(hv.y - bf2f((unsigned short)(hh >> 16))) << 16);
            }
            #pragma unroll
            for (int it = 0; it < 4; ++it) {
                int i = t + 256 * it;
                int row = i >> 5, d = i & 31;
                Xs_u[row * PITCH_DW + 128 + d] = nb1u[(size_t)(node0 + row) * 64 + d];
            }
        } else {
            // ---- stage chunk 1: nb1[32:64dw] (dw 0..31), nb2_hi (32..95), nb2_lo (96..159)
            #pragma unroll
            for (int it = 0; it < 4; ++it) {
                int i = t + 256 * it;
                int row = i >> 5, d = i & 31;
                Xs_u[row * PITCH_DW + d] = nb1u[(size_t)(node0 + row) * 64 + 32 + d];
            }
            #pragma unroll
            for (int it = 0; it < 8; ++it) {
                int i = t + 256 * it;
                int row = i >> 6, d = i & 63;
                size_t g = (size_t)(node0 + row) * 64 + d;
                float2 nv = reinterpret_cast<const float2*>(nb2f)[g];
                unsigned short n0 = f2bf(nv.x), n1 = f2bf(nv.y);
                int lb = row * PITCH_DW;
                Xs_u[lb + 32 + d] = (unsigned)n0 | ((unsigned)n1 << 16);
                Xs_u[lb + 96 + d] = (unsigned)f2bf(nv.x - bf2f(n0))
                                  | ((unsigned)f2bf(nv.y - bf2f(n1)) << 16);
            }
        }
        __syncthreads();

        bf16x8 bfr[2][10];
        #pragma unroll
        for (int nt = 0; nt < 2; ++nt) {
            const unsigned short* wp =
                wcbf + (size_t)(obase + nt * 16 + lm) * KTOT + c * 320 + quad * 8;
            #pragma unroll
            for (int s = 0; s < 10; ++s)
                bfr[nt][s] = *reinterpret_cast<const bf16x8*>(wp + s * 32);
        }
        #pragma unroll
        for (int s = 0; s < 10; ++s) {
            int koff = s * 32 + quad * 8;
            bf16x8 a0 = *reinterpret_cast<const bf16x8*>(&Xs[(0 * 16 + lm) * PITCH_US + koff]);
            bf16x8 a1 = *reinterpret_cast<const bf16x8*>(&Xs[(1 * 16 + lm) * PITCH_US + koff]);
            acc[0][0] = __builtin_amdgcn_mfma_f32_16x16x32_bf16(a0, bfr[0][s], acc[0][0], 0, 0, 0);
            acc[0][1] = __builtin_amdgcn_mfma_f32_16x16x32_bf16(a0, bfr[1][s], acc[0][1], 0, 0, 0);
            acc[1][0] = __builtin_amdgcn_mfma_f32_16x16x32_bf16(a1, bfr[0][s], acc[1][0], 0, 0, 0);
            acc[1][1] = __builtin_amdgcn_mfma_f32_16x16x32_bf16(a1, bfr[1][s], acc[1][1], 0, 0, 0);
        }
        __syncthreads();   // safe to restage / proceed
    }

    // ---- LN: add bias; per-row partial sums via lm-butterfly; cross-wave via LDS
    float bv0 = bias[obase + lm], bv1 = bias[obase + 16 + lm];
    #pragma unroll
    for (int mt = 0; mt < 2; ++mt) {
        float s[4], q[4];
        #pragma unroll
        for (int r = 0; r < 4; ++r) {
            float v0 = acc[mt][0][r] + bv0;
            float v1 = acc[mt][1][r] + bv1;
            acc[mt][0][r] = v0;  acc[mt][1][r] = v1;
            s[r] = v0 + v1;
            q[r] = v0 * v0 + v1 * v1;
        }
        #pragma unroll
        for (int off = 1; off < 16; off <<= 1) {
            #pragma unroll
            for (int r = 0; r < 4; ++r) {
                s[r] += __shfl_xor(s[r], off, 64);
                q[r] += __shfl_xor(q[r], off, 64);
            }
        }
        if (lm == 0) {
            #pragma unroll
            for (int r = 0; r < 4; ++r) {
                part_s[wv][mt * 16 + quad * 4 + r] = s[r];
                part_q[wv][mt * 16 + quad * 4 + r] = q[r];
            }
        }
    }
    __syncthreads();
    if (t < 32) {
        float s = part_s[0][t] + part_s[1][t] + part_s[2][t] + part_s[3][t];
        float q = part_q[0][t] + part_q[1][t] + part_q[2][t] + part_q[3][t];
        float m = s * (1.f / 128.f);
        float var = q * (1.f / 128.f) - m * m;
        mu_s[t] = m;
        rs_s[t] = rsqrtf(var + LN_EPS);
    }
    __syncthreads();

    float g0 = gamma[obase + lm], g1 = gamma[obase + 16 + lm];
    float e0 = beta[obase + lm],  e1 = beta[obase + 16 + lm];
    #pragma unroll
    for (int mt = 0; mt < 2; ++mt) {
        #pragma unroll
        for (int r = 0; r < 4; ++r) {
            int lrow = mt * 16 + quad * 4 + r;
            float mu = mu_s[lrow], rs = rs_s[lrow];
            size_t ro = (size_t)(node0 + lrow) * D;
            out[ro + obase + lm]      = (acc[mt][0][r] - mu) * rs * g0 + e0;
            out[ro + obase + 16 + lm] = (acc[mt][1][r] - mu) * rs * g1 + e1;
        }
    }
}

extern "C" void kernel_launch(void* const* d_in, const int* in_sizes, int n_in,
                              void* d_out, int out_size, void* d_ws, size_t ws_size,
                              hipStream_t stream) {
    const float* h      = (const float*)d_in[0];
    const int*   ei     = (const int*)d_in[1];
    const float* deg    = (const float*)d_in[2];
    const float* Wself  = (const float*)d_in[3];
    const float* Wnb1   = (const float*)d_in[4];
    const float* Whp    = (const float*)d_in[5];
    const float* Wnb2   = (const float*)d_in[6];
    const float* bias   = (const float*)d_in[7];
    const float* logits = (const float*)d_in[8];
    const float* gamma  = (const float*)d_in[9];
    const float* beta   = (const float*)d_in[10];
    float* out = (float*)d_out;

    char* ws = (char*)d_ws;
    int* off                 = (int*)(ws + WS_OFF_OFF);
    int* cur                 = (int*)(ws + WS_OFF_CUR);
    int* bsum                = (int*)(ws + WS_OFF_BSUM);
    int* gcur                = (int*)(ws + WS_OFF_GCUR);
    unsigned short* wcbf     = (unsigned short*)(ws + WS_OFF_WCBF);
    int* esrc                = (int*)(ws + WS_OFF_ESRC);
    int2* gbuf               = (int2*)(ws + WS_OFF_GBUF);
    unsigned int* hhi        = (unsigned int*)(ws + WS_OFF_HHI);
    unsigned int* nb1u       = (unsigned int*)(ws + WS_OFF_NB1);

    const int* src = ei;
    const int* dst = ei + NE;

    hipMemsetAsync(cur, 0, NN * sizeof(int), stream);
    hipMemsetAsync(gcur, 0, NBK * sizeof(int), stream);

    k_weights<<<64, 256, 0, stream>>>(Wself, Wnb1, Whp, Wnb2, logits, wcbf);
    k_scan1<<<NSB, 256, 0, stream>>>(deg, off, bsum);
    k_scan2<<<1, 64, 0, stream>>>(bsum);
    k_scan3<<<(NN + 255) / 256, 256, 0, stream>>>(off, bsum);
    k_bin<<<(NE + 2047) / 2048, 256, 0, stream>>>(src, dst, gcur, gbuf);
    k_scatter2<<<NBK, 1024, 0, stream>>>(gbuf, gcur, off, cur, esrc);

    // prep AFTER scatter2: hhi overlays the (now dead) gbuf region
    k_prep<<<25000, 256, 0, stream>>>(h, hhi);

    // hop1: gather h_hi (bf16) -> nb1_hi (bf16, ws)
    k_hop<false><<<(NN * 64) / 256, 256, 0, stream>>>(hhi, (void*)nb1u, off, cur, esrc, deg);
    // hop2: gather nb1_hi (bf16) -> nb2 (fp32, d_out scratch; gemm block reads
    // only its own rows then overwrites them — self-contained)
    k_hop<true><<<(NN * 64) / 256, 256, 0, stream>>>(nb1u, (void*)out, off, cur, esrc, deg);

    k_gemm_ln<<<NN / 32, 256, 0, stream>>>(hhi, h, nb1u, out, wcbf, bias, gamma, beta, out);
}